// Round 7
// baseline (65.725 us; speedup 1.0000x reference)
//
#include <hip/hip_runtime.h>
#include <hip/hip_bf16.h>
#include <stdint.h>

// GPTQ 4-bit fused dequant + GEMM.  x[128,4096]f32 @ W[4096,11008] -> out[128,11008]f32
// W[k][n] = scales[k/128][n] * nibble(qweight[k/8][n], k%8) - zeros[k/128][n]
//
// R7 = R6 with the compile fix (__floats2bfloat162_rn doesn't exist in ROCm 7.2;
//      use our own RNE packer f2bf_pack).
// ZERO-LDS design. One qweight int32 == one MFMA B-frag half (8 k-nibbles
// at one col) -> dequant in-register into B fragments. A-frags direct from
// global (L1-shared across the block's 4 waves). mfma_f32_32x32x16_bf16,
// wave tile 64x32, block 4 waves = 128 cols, grid 86n x 2m x SPLIT4 = 688.
// No barriers; q prefetch 3-deep.

#define IN_F   4096
#define OUT_F  11008
#define BATCH  128
#define SPLIT  4
#define KSLICE (IN_F / SPLIT)   // 1024
#define NCH    (KSLICE / 64)    // 16 chunks of 64 k
#define NBN    86               // n-blocks (128 cols each)
#define NBLK   (NBN * 2 * SPLIT)// 688
#define MN     (BATCH * OUT_F)  // 1409024

typedef __attribute__((ext_vector_type(8)))  short short8;
typedef __attribute__((ext_vector_type(16))) float f32x16;

static __device__ __forceinline__ unsigned int f2bf_pack(float lo, float hi) {
  // round-to-nearest-even bf16 pair packed into one u32
  unsigned int a = __float_as_uint(lo);
  unsigned int b = __float_as_uint(hi);
  a += 0x7FFFu + ((a >> 16) & 1u);
  b += 0x7FFFu + ((b >> 16) & 1u);
  return (a >> 16) | (b & 0xFFFF0000u);
}

__global__ __launch_bounds__(256) void cvt_kernel(const float* __restrict__ x,
                                                  unsigned int* __restrict__ xb) {
  int i = blockIdx.x * 256 + threadIdx.x;
  float4 v0 = *(const float4*)(x + (size_t)i * 8);
  float4 v1 = *(const float4*)(x + (size_t)i * 8 + 4);
  uint4 o;
  o.x = f2bf_pack(v0.x, v0.y);
  o.y = f2bf_pack(v0.z, v0.w);
  o.z = f2bf_pack(v1.x, v1.y);
  o.w = f2bf_pack(v1.z, v1.w);
  *(uint4*)(xb + (size_t)i * 4) = o;
}

__global__ __launch_bounds__(256) void zero_out(float* __restrict__ out) {
  int base = (blockIdx.x * 256 + threadIdx.x) * 16;   // 344 blocks
  float4 z = {0.f, 0.f, 0.f, 0.f};
#pragma unroll
  for (int j = 0; j < 4; ++j) *(float4*)(out + base + j * 4) = z;
}

__global__ __launch_bounds__(256) void reduce_kernel(const float* __restrict__ part,
                                                     float* __restrict__ out) {
  int base = (blockIdx.x * 256 + threadIdx.x) * 8;    // 688 blocks
  float4 s0 = {0.f, 0.f, 0.f, 0.f}, s1 = s0;
#pragma unroll
  for (int s = 0; s < SPLIT; ++s) {
    const float* p = part + (size_t)s * MN + base;
    float4 a = *(const float4*)(p);
    float4 b = *(const float4*)(p + 4);
    s0.x += a.x; s0.y += a.y; s0.z += a.z; s0.w += a.w;
    s1.x += b.x; s1.y += b.y; s1.z += b.z; s1.w += b.w;
  }
  *(float4*)(out + base)     = s0;
  *(float4*)(out + base + 4) = s1;
}

// dequant one packed int32 (8 k-nibbles at one col) into a bf16 B-fragment
static __device__ __forceinline__ short8 deq8(unsigned int q, float s, float z) {
  float f[8];
#pragma unroll
  for (int j = 0; j < 8; ++j)
    f[j] = s * (float)((q >> (4 * j)) & 0xFu) - z;
  union { unsigned int u[4]; short8 s8; } r;
#pragma unroll
  for (int j = 0; j < 4; ++j)
    r.u[j] = f2bf_pack(f[2 * j], f[2 * j + 1]);
  return r.s8;
}

// load 4 q-words (one chunk's B data for this lane) into prefetch set S
#define LOAD_Q(S, CC) do {                                                     \
    _Pragma("unroll")                                                          \
    for (int ks_ = 0; ks_ < 4; ++ks_)                                          \
      qP[S][ks_] = qlane[(size_t)((CC) * 8 + ks_ * 2) * OUT_F];                \
  } while (0)

__global__ __launch_bounds__(256) void gptq_gemm(
    const unsigned short* __restrict__ xb,  // [128,4096] bf16
    const int* __restrict__ qweight,        // [512, 11008]
    const float* __restrict__ scales,       // [32, 11008]
    const float* __restrict__ zeros,        // [32, 11008]
    float* __restrict__ outp,               // out (atomic) or partials base
    int atomic_mode) {
  const int tid  = threadIdx.x;
  const int lane = tid & 63;
  const int wid  = tid >> 6;
  const int hi   = lane >> 5;          // 0/1: k-half within fragment
  const int lo32 = lane & 31;

  const int nb = blockIdx.x % NBN;
  const int mb = (blockIdx.x / NBN) & 1;
  const int sl = blockIdx.x / (NBN * 2);

  const int ncol = nb * 128 + wid * 32 + lo32;  // this lane's output column
  const int m0   = mb * 64;                     // wave rows m0..m0+63
  const int k0   = sl * KSLICE;

  float* dst = atomic_mode ? outp : outp + (size_t)sl * MN;

  // per-lane scale/zero for the 8 groups of this K-slice (group = 128 k = 2 chunks)
  float sreg[8], zreg[8];
#pragma unroll
  for (int g = 0; g < 8; ++g) {
    sreg[g] = scales[(size_t)(sl * 8 + g) * OUT_F + ncol];
    zreg[g] = zeros [(size_t)(sl * 8 + g) * OUT_F + ncol];
  }

  // base pointers
  const int* qlane = qweight + (size_t)(sl * (KSLICE / 8) + hi) * OUT_F + ncol;
  const unsigned short* aPtr0 = xb + (size_t)(m0 +      lo32) * IN_F + k0 + hi * 8;
  const unsigned short* aPtr1 = xb + (size_t)(m0 + 32 + lo32) * IN_F + k0 + hi * 8;

  unsigned int qP[3][4];
  LOAD_Q(0, 0);
  LOAD_Q(1, 1);
  LOAD_Q(2, 2);

  f32x16 acc[2] = {};

#pragma unroll
  for (int cc = 0; cc < NCH; ++cc) {
    // A fragments for this chunk: 8 x 16B direct loads (L1-shared in block)
    uint4 aF[2][4];
#pragma unroll
    for (int ks = 0; ks < 4; ++ks) {
      aF[0][ks] = *(const uint4*)(aPtr0 + cc * 64 + ks * 16);
      aF[1][ks] = *(const uint4*)(aPtr1 + cc * 64 + ks * 16);
    }

    // dequant chunk cc's q-words (covers A-load latency with VALU)
    const float s = sreg[cc >> 1], z = zreg[cc >> 1];
    short8 bF[4];
#pragma unroll
    for (int ks = 0; ks < 4; ++ks)
      bF[ks] = deq8(qP[cc % 3][ks], s, z);

    // prefetch chunk cc+3's q-words into the just-freed set
    if (cc + 3 < NCH) LOAD_Q(cc % 3, cc + 3);

    // 8 MFMAs (k = 4 x 16)
#pragma unroll
    for (int ks = 0; ks < 4; ++ks) {
      union { uint4 u; short8 s8; } a0, a1;
      a0.u = aF[0][ks];
      a1.u = aF[1][ks];
      acc[0] = __builtin_amdgcn_mfma_f32_32x32x16_bf16(a0.s8, bF[ks], acc[0], 0, 0, 0);
      acc[1] = __builtin_amdgcn_mfma_f32_32x32x16_bf16(a1.s8, bF[ks], acc[1], 0, 0, 0);
    }
  }

  // epilogue: C/D layout col=lane&31, row=(reg&3)+8*(reg>>2)+4*(lane>>5)
#pragma unroll
  for (int rt = 0; rt < 2; ++rt) {
#pragma unroll
    for (int reg = 0; reg < 16; ++reg) {
      int row = m0 + rt * 32 + 4 * hi + (reg & 3) + 8 * (reg >> 2);
      if (atomic_mode) {
        atomicAdd(dst + (size_t)row * OUT_F + ncol, acc[rt][reg]);
      } else {
        dst[(size_t)row * OUT_F + ncol] = acc[rt][reg];
      }
    }
  }
}

extern "C" void kernel_launch(void* const* d_in, const int* in_sizes, int n_in,
                              void* d_out, int out_size, void* d_ws, size_t ws_size,
                              hipStream_t stream) {
  const float* x       = (const float*)d_in[0];
  const int*   qweight = (const int*)d_in[1];
  const float* scales  = (const float*)d_in[2];
  const float* zeros   = (const float*)d_in[3];
  float*       outp    = (float*)d_out;

  const size_t xb_bytes   = (size_t)BATCH * IN_F * sizeof(unsigned short);  // 1 MB
  const size_t part_bytes = (size_t)SPLIT * MN * sizeof(float);             // 22.5 MB
  int partials = (ws_size >= xb_bytes + part_bytes) ? 1 : 0;

  unsigned short* xb   = (unsigned short*)d_ws;
  float*          part = (float*)((char*)d_ws + xb_bytes);

  // x f32 -> bf16 (1 MB): 128*4096 elems, 8/thread -> 256 blocks
  cvt_kernel<<<256, 256, 0, stream>>>(x, (unsigned int*)d_ws);

  if (partials) {
    gptq_gemm<<<NBLK, 256, 0, stream>>>(xb, qweight, scales, zeros, part, 0);
    reduce_kernel<<<688, 256, 0, stream>>>(part, outp);
  } else {
    zero_out<<<344, 256, 0, stream>>>(outp);
    gptq_gemm<<<NBLK, 256, 0, stream>>>(xb, qweight, scales, zeros, outp, 1);
  }
}

// Round 8
// 43.301 us; speedup vs baseline: 1.5179x; 1.5179x over previous
//
#include <hip/hip_runtime.h>
#include <hip/hip_bf16.h>
#include <stdint.h>

// GPTQ 4-bit fused dequant + GEMM.  x[128,4096]f32 @ W[4096,11008] -> out[128,11008]f32
// W[k][n] = scales[k/128][n] * nibble(qweight[k/8][n], k%8) - zeros[k/128][n]
//
// R8 = R7 (zero-LDS, in-reg B dequant, 32x32x16 MFMA, no barriers) + the A-path
//     fix: cvt kernel pre-swizzles x into FRAGMENT-MAJOR order xs[mt][cg][ks][lane],
//     so every A-frag load is wave-uniform base + lane*16B (coalesced 1KB, zero
//     gather). R7's aF load was a 64-line gather (stride-8KB rows) -> L1/TA
//     serialization = the 57us stall. xs is 1MB -> L2-resident, shared by all
//     86 n-blocks.

#define IN_F   4096
#define OUT_F  11008
#define BATCH  128
#define SPLIT  4
#define KSLICE (IN_F / SPLIT)   // 1024
#define NCH    (KSLICE / 64)    // 16 chunks of 64 k
#define NCHG   (IN_F / 64)      // 64 global chunks
#define NBN    86               // n-blocks (128 cols each)
#define NBLK   (NBN * 2 * SPLIT)// 688
#define MN     (BATCH * OUT_F)  // 1409024

typedef __attribute__((ext_vector_type(8)))  short short8;
typedef __attribute__((ext_vector_type(16))) float f32x16;

static __device__ __forceinline__ unsigned int f2bf_pack(float lo, float hi) {
  // round-to-nearest-even bf16 pair packed into one u32
  unsigned int a = __float_as_uint(lo);
  unsigned int b = __float_as_uint(hi);
  a += 0x7FFFu + ((a >> 16) & 1u);
  b += 0x7FFFu + ((b >> 16) & 1u);
  return (a >> 16) | (b & 0xFFFF0000u);
}

// x[128][4096] f32 -> xs in fragment-major order:
//   16B unit index = ((mt*64 + cg)*4 + ks)*64 + lane,  lane = hi*32 + lo32
//   holding x[mt*32 + lo32][cg*64 + ks*16 + hi*8 + 0..7] as bf16.
__global__ __launch_bounds__(256) void cvt_swz(const float* __restrict__ x,
                                               uint4* __restrict__ xs) {
  int t  = blockIdx.x * 256 + threadIdx.x;   // 65536 threads
  int m  = t >> 9;                           // 0..127
  int k  = (t & 511) * 8;                    // 0..4088, step 8
  float4 u0 = *(const float4*)(x + (size_t)m * IN_F + k);
  float4 u1 = *(const float4*)(x + (size_t)m * IN_F + k + 4);
  uint4 o;
  o.x = f2bf_pack(u0.x, u0.y);
  o.y = f2bf_pack(u0.z, u0.w);
  o.z = f2bf_pack(u1.x, u1.y);
  o.w = f2bf_pack(u1.z, u1.w);
  int mt = m >> 5, lo32 = m & 31;
  int cg = k >> 6, ks = (k >> 4) & 3, hi = (k >> 3) & 1;
  size_t idx = (size_t)(((mt * NCHG + cg) * 4 + ks) << 6) + hi * 32 + lo32;
  xs[idx] = o;
}

__global__ __launch_bounds__(256) void zero_out(float* __restrict__ out) {
  int base = (blockIdx.x * 256 + threadIdx.x) * 16;   // 344 blocks
  float4 z = {0.f, 0.f, 0.f, 0.f};
#pragma unroll
  for (int j = 0; j < 4; ++j) *(float4*)(out + base + j * 4) = z;
}

__global__ __launch_bounds__(256) void reduce_kernel(const float* __restrict__ part,
                                                     float* __restrict__ out) {
  int base = (blockIdx.x * 256 + threadIdx.x) * 8;    // 688 blocks
  float4 s0 = {0.f, 0.f, 0.f, 0.f}, s1 = s0;
#pragma unroll
  for (int s = 0; s < SPLIT; ++s) {
    const float* p = part + (size_t)s * MN + base;
    float4 a = *(const float4*)(p);
    float4 b = *(const float4*)(p + 4);
    s0.x += a.x; s0.y += a.y; s0.z += a.z; s0.w += a.w;
    s1.x += b.x; s1.y += b.y; s1.z += b.z; s1.w += b.w;
  }
  *(float4*)(out + base)     = s0;
  *(float4*)(out + base + 4) = s1;
}

// dequant one packed int32 (8 k-nibbles at one col) into a bf16 B-fragment
static __device__ __forceinline__ short8 deq8(unsigned int q, float s, float z) {
  float f[8];
#pragma unroll
  for (int j = 0; j < 8; ++j)
    f[j] = s * (float)((q >> (4 * j)) & 0xFu) - z;
  union { unsigned int u[4]; short8 s8; } r;
#pragma unroll
  for (int j = 0; j < 4; ++j)
    r.u[j] = f2bf_pack(f[2 * j], f[2 * j + 1]);
  return r.s8;
}

// load 4 q-words (one chunk's B data for this lane) into prefetch set S
#define LOAD_Q(S, CC) do {                                                     \
    _Pragma("unroll")                                                          \
    for (int ks_ = 0; ks_ < 4; ++ks_)                                          \
      qP[S][ks_] = qlane[(size_t)((CC) * 8 + ks_ * 2) * OUT_F];                \
  } while (0)

__global__ __launch_bounds__(256) void gptq_gemm(
    const uint4* __restrict__ xs,           // frag-major x (bf16)
    const int* __restrict__ qweight,        // [512, 11008]
    const float* __restrict__ scales,       // [32, 11008]
    const float* __restrict__ zeros,        // [32, 11008]
    float* __restrict__ outp,               // out (atomic) or partials base
    int atomic_mode) {
  const int tid  = threadIdx.x;
  const int lane = tid & 63;
  const int wid  = tid >> 6;
  const int hi   = lane >> 5;          // 0/1: k-half within fragment
  const int lo32 = lane & 31;

  const int nb = blockIdx.x % NBN;
  const int mb = (blockIdx.x / NBN) & 1;
  const int sl = blockIdx.x / (NBN * 2);

  const int ncol = nb * 128 + wid * 32 + lo32;  // this lane's output column
  const int m0   = mb * 64;                     // wave rows m0..m0+63

  float* dst = atomic_mode ? outp : outp + (size_t)sl * MN;

  // per-lane scale/zero for the 8 groups of this K-slice (group = 128 k = 2 chunks)
  float sreg[8], zreg[8];
#pragma unroll
  for (int g = 0; g < 8; ++g) {
    sreg[g] = scales[(size_t)(sl * 8 + g) * OUT_F + ncol];
    zreg[g] = zeros [(size_t)(sl * 8 + g) * OUT_F + ncol];
  }

  // base pointers
  const int* qlane = qweight + (size_t)(sl * (KSLICE / 8) + hi) * OUT_F + ncol;
  // A-frag bases (16B-unit index): ((mt*NCHG + cg)*4 + ks)*64 + lane
  const uint4* aB0 = xs + (size_t)(((mb * 2 + 0) * NCHG + sl * NCH) << 8) + lane;
  const uint4* aB1 = xs + (size_t)(((mb * 2 + 1) * NCHG + sl * NCH) << 8) + lane;

  unsigned int qP[3][4];
  LOAD_Q(0, 0);
  LOAD_Q(1, 1);
  LOAD_Q(2, 2);

  f32x16 acc[2] = {};

#pragma unroll
  for (int cc = 0; cc < NCH; ++cc) {
    // A fragments: coalesced (base + lane*16B), xs is L2-resident
    uint4 aF[2][4];
#pragma unroll
    for (int ks = 0; ks < 4; ++ks) {
      aF[0][ks] = aB0[(size_t)(cc * 4 + ks) << 6];
      aF[1][ks] = aB1[(size_t)(cc * 4 + ks) << 6];
    }

    // dequant chunk cc's q-words (covers A-load latency with VALU)
    const float s = sreg[cc >> 1], z = zreg[cc >> 1];
    short8 bF[4];
#pragma unroll
    for (int ks = 0; ks < 4; ++ks)
      bF[ks] = deq8(qP[cc % 3][ks], s, z);

    // prefetch chunk cc+3's q-words into the just-freed set
    if (cc + 3 < NCH) LOAD_Q(cc % 3, cc + 3);

    // 8 MFMAs (k = 4 x 16)
#pragma unroll
    for (int ks = 0; ks < 4; ++ks) {
      union { uint4 u; short8 s8; } a0, a1;
      a0.u = aF[0][ks];
      a1.u = aF[1][ks];
      acc[0] = __builtin_amdgcn_mfma_f32_32x32x16_bf16(a0.s8, bF[ks], acc[0], 0, 0, 0);
      acc[1] = __builtin_amdgcn_mfma_f32_32x32x16_bf16(a1.s8, bF[ks], acc[1], 0, 0, 0);
    }
  }

  // epilogue: C/D layout col=lane&31, row=(reg&3)+8*(reg>>2)+4*(lane>>5)
#pragma unroll
  for (int rt = 0; rt < 2; ++rt) {
#pragma unroll
    for (int reg = 0; reg < 16; ++reg) {
      int row = m0 + rt * 32 + 4 * hi + (reg & 3) + 8 * (reg >> 2);
      if (atomic_mode) {
        atomicAdd(dst + (size_t)row * OUT_F + ncol, acc[rt][reg]);
      } else {
        dst[(size_t)row * OUT_F + ncol] = acc[rt][reg];
      }
    }
  }
}

extern "C" void kernel_launch(void* const* d_in, const int* in_sizes, int n_in,
                              void* d_out, int out_size, void* d_ws, size_t ws_size,
                              hipStream_t stream) {
  const float* x       = (const float*)d_in[0];
  const int*   qweight = (const int*)d_in[1];
  const float* scales  = (const float*)d_in[2];
  const float* zeros   = (const float*)d_in[3];
  float*       outp    = (float*)d_out;

  const size_t xs_bytes   = (size_t)BATCH * IN_F * sizeof(unsigned short);  // 1 MB
  const size_t part_bytes = (size_t)SPLIT * MN * sizeof(float);             // 22.5 MB
  int partials = (ws_size >= xs_bytes + part_bytes) ? 1 : 0;

  uint4* xs   = (uint4*)d_ws;
  float* part = (float*)((char*)d_ws + xs_bytes);

  // x f32 -> frag-major bf16 (1 MB): 128*4096 elems, 8/thread -> 256 blocks
  cvt_swz<<<256, 256, 0, stream>>>(x, xs);

  if (partials) {
    gptq_gemm<<<NBLK, 256, 0, stream>>>(xs, qweight, scales, zeros, part, 0);
    reduce_kernel<<<688, 256, 0, stream>>>(part, outp);
  } else {
    zero_out<<<344, 256, 0, stream>>>(outp);
    gptq_gemm<<<NBLK, 256, 0, stream>>>(xs, qweight, scales, zeros, outp, 1);
  }
}